// Round 1
// baseline (612.435 us; speedup 1.0000x reference)
//
#include <hip/hip_runtime.h>
#include <stdint.h>

#define S_LEN 2048
#define D_EMBD 1024
#define N_HEADS 16
#define D_HEAD 64
#define B_SZ 4
#define M_TOT (B_SZ * S_LEN)   // 8192

typedef __bf16 bf16x8 __attribute__((ext_vector_type(8)));
typedef float f32x4 __attribute__((ext_vector_type(4)));
typedef unsigned short u16x8 __attribute__((ext_vector_type(8)));

__device__ __forceinline__ unsigned short f2bf(float f) {
  unsigned u = __builtin_bit_cast(unsigned, f);
  u += 0x7fffu + ((u >> 16) & 1u);
  return (unsigned short)(u >> 16);
}

__device__ __forceinline__ void async16(const void* g, void* l) {
  __builtin_amdgcn_global_load_lds(
      (const __attribute__((address_space(1))) void*)(uintptr_t)g,
      (__attribute__((address_space(3))) void*)(unsigned)(uintptr_t)l,
      16, 0, 0);
}

__device__ __forceinline__ f32x4 mfma16(bf16x8 a, bf16x8 b, f32x4 c) {
  return __builtin_amdgcn_mfma_f32_16x16x32_bf16(a, b, c, 0, 0, 0);
}

__global__ __launch_bounds__(256) void cast_bf16_kernel(
    const float* __restrict__ in, unsigned short* __restrict__ out, int n8) {
  int i = blockIdx.x * 256 + threadIdx.x;
  if (i >= n8) return;
  size_t base = (size_t)i * 8;
  float4 a = *(const float4*)(in + base);
  float4 b = *(const float4*)(in + base + 4);
  u16x8 r;
  r[0] = f2bf(a.x); r[1] = f2bf(a.y); r[2] = f2bf(a.z); r[3] = f2bf(a.w);
  r[4] = f2bf(b.x); r[5] = f2bf(b.y); r[6] = f2bf(b.z); r[7] = f2bf(b.w);
  *(u16x8*)(out + base) = r;
}

// C = A[M,K] @ W[N,K]^T
// MODE 0: bf16 out, [B,H,S,Dh] layout   (Q, K projections)
// MODE 1: f32 out,  [M,N] row-major     (final output)
// MODE 2: bf16 out, [B,H,Dh,S] layout   (V projection, transposed)
template <int MODE>
__global__ __launch_bounds__(256) void gemm_bt(
    const unsigned short* __restrict__ A, const unsigned short* __restrict__ W,
    void* __restrict__ out, int M, int N, int K) {
  __shared__ __align__(16) unsigned short As[128 * 64];
  __shared__ __align__(16) unsigned short Bs[128 * 64];
  const int tid = threadIdx.x;
  const int lane = tid & 63;
  const int w = tid >> 6;
  const int wr = w >> 1, wc = w & 1;
  const int li = lane & 15, g = lane >> 4;
  const int bm = blockIdx.y, bn = blockIdx.x;

  f32x4 acc[4][4];
  #pragma unroll
  for (int i = 0; i < 4; i++)
    #pragma unroll
    for (int j = 0; j < 4; j++)
      #pragma unroll
      for (int r = 0; r < 4; r++) acc[i][j][r] = 0.f;

  const int srow = w * 32 + (lane >> 3);   // row this lane stages (plus p*8)
  const int scol = (lane & 7) * 8;         // k-offset this lane stages

  for (int k0 = 0; k0 < K; k0 += 64) {
    #pragma unroll
    for (int p = 0; p < 4; ++p) {
      int r = srow + p * 8;
      // LDS dest must be the wave-uniform base; HW adds lane*16.
      async16(&A[(size_t)(bm * 128 + r) * K + k0 + scol], &As[(w * 32 + p * 8) * 64]);
      async16(&W[(size_t)(bn * 128 + r) * K + k0 + scol], &Bs[(w * 32 + p * 8) * 64]);
    }
    __syncthreads();   // drains vmcnt (global_load_lds) before reads
    #pragma unroll
    for (int kk = 0; kk < 2; ++kk) {
      bf16x8 a[4], b[4];
      #pragma unroll
      for (int i = 0; i < 4; i++)
        a[i] = *(const bf16x8*)&As[(wr * 64 + i * 16 + li) * 64 + kk * 32 + g * 8];
      #pragma unroll
      for (int j = 0; j < 4; j++)
        b[j] = *(const bf16x8*)&Bs[(wc * 64 + j * 16 + li) * 64 + kk * 32 + g * 8];
      #pragma unroll
      for (int i = 0; i < 4; i++)
        #pragma unroll
        for (int j = 0; j < 4; j++)
          acc[i][j] = mfma16(a[i], b[j], acc[i][j]);
    }
    __syncthreads();   // protect LDS before next stage overwrites
  }

  #pragma unroll
  for (int i = 0; i < 4; i++)
    #pragma unroll
    for (int j = 0; j < 4; j++)
      #pragma unroll
      for (int r = 0; r < 4; r++) {
        int row = bm * 128 + wr * 64 + i * 16 + g * 4 + r;  // m index
        int col = bn * 128 + wc * 64 + j * 16 + li;          // n index
        float v = acc[i][j][r];
        if constexpr (MODE == 0) {
          // [B,H,S,Dh]: b=row>>11, s=row&2047, h=col>>6, d=col&63
          size_t idx = ((size_t)((row >> 11) * N_HEADS + (col >> 6)) * S_LEN +
                        (row & (S_LEN - 1))) * D_HEAD + (col & (D_HEAD - 1));
          ((unsigned short*)out)[idx] = f2bf(v);
        } else if constexpr (MODE == 1) {
          ((float*)out)[(size_t)row * N + col] = v;
        } else {
          // [B,H,Dh,S]
          size_t idx = ((size_t)((row >> 11) * N_HEADS + (col >> 6)) * D_HEAD +
                        (col & (D_HEAD - 1))) * S_LEN + (row & (S_LEN - 1));
          ((unsigned short*)out)[idx] = f2bf(v);
        }
      }
}

// Flash attention: grid (S/64, B*H), 256 thr. Wave w owns 16 q-rows.
// qh,kh: [B,H,S,64] bf16. vt: [B,H,64,S] bf16. xout: [B,S,E] bf16.
__global__ __launch_bounds__(256) void attn_kernel(
    const unsigned short* __restrict__ qh, const unsigned short* __restrict__ kh,
    const unsigned short* __restrict__ vt, unsigned short* __restrict__ xout) {
  __shared__ __align__(16) unsigned short P_lds[4][16 * 32];
  const int lane = threadIdx.x & 63;
  const int w = threadIdx.x >> 6;
  const int bh = blockIdx.y;
  const int qb = blockIdx.x * 64 + w * 16;
  const int g = lane >> 4, li = lane & 15;

  const unsigned short* Q = qh + (size_t)bh * S_LEN * D_HEAD;
  const unsigned short* Kp = kh + (size_t)bh * S_LEN * D_HEAD;
  const unsigned short* Vt = vt + (size_t)bh * D_HEAD * S_LEN;

  // Q A-frags: lane holds Q[qb+li][g*8+j (+32)]
  bf16x8 qf0 = *(const bf16x8*)&Q[(qb + li) * 64 + g * 8];
  bf16x8 qf1 = *(const bf16x8*)&Q[(qb + li) * 64 + 32 + g * 8];

  f32x4 o[4];
  #pragma unroll
  for (int dt = 0; dt < 4; dt++)
    #pragma unroll
    for (int r = 0; r < 4; r++) o[dt][r] = 0.f;
  float m[4] = {-1e30f, -1e30f, -1e30f, -1e30f};
  float lsum[4] = {0.f, 0.f, 0.f, 0.f};

  for (int kv = 0; kv < S_LEN; kv += 32) {
    // K B-frags: lane holds K[kv+c*16+li][g*8+j (+32)]
    bf16x8 k00 = *(const bf16x8*)&Kp[(kv + li) * 64 + g * 8];
    bf16x8 k01 = *(const bf16x8*)&Kp[(kv + li) * 64 + 32 + g * 8];
    bf16x8 k10 = *(const bf16x8*)&Kp[(kv + 16 + li) * 64 + g * 8];
    bf16x8 k11 = *(const bf16x8*)&Kp[(kv + 16 + li) * 64 + 32 + g * 8];
    f32x4 s0, s1;
    #pragma unroll
    for (int r = 0; r < 4; r++) { s0[r] = 0.f; s1[r] = 0.f; }
    s0 = mfma16(qf0, k00, s0); s0 = mfma16(qf1, k01, s0);
    s1 = mfma16(qf0, k10, s1); s1 = mfma16(qf1, k11, s1);
    // lane now holds S[q = qb + g*4 + r][key = kv (+16) + li]

    #pragma unroll
    for (int r = 0; r < 4; r++) {
      float a = s0[r] * 0.125f, b = s1[r] * 0.125f;  // 1/sqrt(64)
      float t = fmaxf(a, b);
      t = fmaxf(t, __shfl_xor(t, 1));
      t = fmaxf(t, __shfl_xor(t, 2));
      t = fmaxf(t, __shfl_xor(t, 4));
      t = fmaxf(t, __shfl_xor(t, 8));
      float mn = fmaxf(m[r], t);
      float sc = __expf(m[r] - mn);
      float p0 = __expf(a - mn);
      float p1 = __expf(b - mn);
      float ts = p0 + p1;
      ts += __shfl_xor(ts, 1); ts += __shfl_xor(ts, 2);
      ts += __shfl_xor(ts, 4); ts += __shfl_xor(ts, 8);
      lsum[r] = lsum[r] * sc + ts;
      m[r] = mn;
      #pragma unroll
      for (int dt = 0; dt < 4; dt++) o[dt][r] *= sc;
      P_lds[w][(g * 4 + r) * 32 + li] = f2bf(p0);
      P_lds[w][(g * 4 + r) * 32 + 16 + li] = f2bf(p1);
    }
    // wave-private LDS region: just drain DS ops, no block barrier needed
    asm volatile("s_waitcnt lgkmcnt(0)" ::: "memory");
    // P A-frag: lane holds P[li][g*8+j]
    bf16x8 pa = *(const bf16x8*)&P_lds[w][li * 32 + g * 8];
    #pragma unroll
    for (int dt = 0; dt < 4; dt++) {
      // V B-frag: lane holds V[kv+g*8+j][dt*16+li] via transposed layout
      bf16x8 vf = *(const bf16x8*)&Vt[(size_t)(dt * 16 + li) * S_LEN + kv + g * 8];
      o[dt] = mfma16(pa, vf, o[dt]);
    }
  }

  #pragma unroll
  for (int r = 0; r < 4; r++) {
    float inv = 1.0f / lsum[r];
    int srow = qb + g * 4 + r;
    size_t base = ((size_t)(bh >> 4) * S_LEN + srow) * D_EMBD + (size_t)(bh & 15) * D_HEAD;
    #pragma unroll
    for (int dt = 0; dt < 4; dt++)
      xout[base + dt * 16 + li] = f2bf(o[dt][r] * inv);
  }
}

extern "C" void kernel_launch(void* const* d_in, const int* in_sizes, int n_in,
                              void* d_out, int out_size, void* d_ws, size_t ws_size,
                              hipStream_t stream) {
  const float* q   = (const float*)d_in[0];
  const float* k   = (const float*)d_in[1];
  const float* v   = (const float*)d_in[2];
  const float* wqf = (const float*)d_in[3];
  const float* wkf = (const float*)d_in[4];
  const float* wvf = (const float*)d_in[5];
  const float* wof = (const float*)d_in[6];

  char* ws = (char*)d_ws;
  unsigned short* castbuf = (unsigned short*)(ws);                 // 16 MB
  unsigned short* qh = (unsigned short*)(ws + (16u << 20));        // 16 MB
  unsigned short* kh = (unsigned short*)(ws + (32u << 20));        // 16 MB
  unsigned short* vt = (unsigned short*)(ws + (48u << 20));        // 16 MB
  unsigned short* ax = (unsigned short*)(ws + (64u << 20));        // 16 MB
  unsigned short* wq = (unsigned short*)(ws + (80u << 20));        // 2 MB
  unsigned short* wk = wq + (1u << 20);
  unsigned short* wv = wk + (1u << 20);
  unsigned short* wo = wv + (1u << 20);

  const int MK8 = M_TOT * D_EMBD / 8;   // 1048576
  const int WK8 = D_EMBD * D_EMBD / 8;  // 131072

  cast_bf16_kernel<<<WK8 / 256, 256, 0, stream>>>(wqf, wq, WK8);
  cast_bf16_kernel<<<WK8 / 256, 256, 0, stream>>>(wkf, wk, WK8);
  cast_bf16_kernel<<<WK8 / 256, 256, 0, stream>>>(wvf, wv, WK8);
  cast_bf16_kernel<<<WK8 / 256, 256, 0, stream>>>(wof, wo, WK8);

  dim3 gg(D_EMBD / 128, M_TOT / 128);  // (8, 64)

  cast_bf16_kernel<<<MK8 / 256, 256, 0, stream>>>(q, castbuf, MK8);
  gemm_bt<0><<<gg, 256, 0, stream>>>(castbuf, wq, qh, M_TOT, D_EMBD, D_EMBD);
  cast_bf16_kernel<<<MK8 / 256, 256, 0, stream>>>(k, castbuf, MK8);
  gemm_bt<0><<<gg, 256, 0, stream>>>(castbuf, wk, kh, M_TOT, D_EMBD, D_EMBD);
  cast_bf16_kernel<<<MK8 / 256, 256, 0, stream>>>(v, castbuf, MK8);
  gemm_bt<2><<<gg, 256, 0, stream>>>(castbuf, wv, vt, M_TOT, D_EMBD, D_EMBD);

  attn_kernel<<<dim3(S_LEN / 64, B_SZ * N_HEADS), 256, 0, stream>>>(qh, kh, vt, ax);

  gemm_bt<1><<<gg, 256, 0, stream>>>(ax, wo, d_out, M_TOT, D_EMBD, D_EMBD);
}

// Round 2
// 389.115 us; speedup vs baseline: 1.5739x; 1.5739x over previous
//
#include <hip/hip_runtime.h>
#include <stdint.h>

#define S_LEN 2048
#define D_EMBD 1024
#define N_HEADS 16
#define D_HEAD 64
#define B_SZ 4
#define M_TOT (B_SZ * S_LEN)   // 8192

typedef __bf16 bf16x8 __attribute__((ext_vector_type(8)));
typedef float f32x4 __attribute__((ext_vector_type(4)));
typedef float f32x16 __attribute__((ext_vector_type(16)));
typedef unsigned short u16x8 __attribute__((ext_vector_type(8)));
typedef unsigned int u32x4 __attribute__((ext_vector_type(4)));

__device__ __forceinline__ unsigned short f2bf(float f) {
  unsigned u = __builtin_bit_cast(unsigned, f);
  u += 0x7fffu + ((u >> 16) & 1u);
  return (unsigned short)(u >> 16);
}

__device__ __forceinline__ void async16(const void* g, void* l) {
  __builtin_amdgcn_global_load_lds(
      (const __attribute__((address_space(1))) void*)(uintptr_t)g,
      (__attribute__((address_space(3))) void*)(unsigned)(uintptr_t)l,
      16, 0, 0);
}

__device__ __forceinline__ f32x4 mfma16(bf16x8 a, bf16x8 b, f32x4 c) {
  return __builtin_amdgcn_mfma_f32_16x16x32_bf16(a, b, c, 0, 0, 0);
}
__device__ __forceinline__ f32x16 mfma32(bf16x8 a, bf16x8 b, f32x16 c) {
  return __builtin_amdgcn_mfma_f32_32x32x16_bf16(a, b, c, 0, 0, 0);
}

__global__ __launch_bounds__(256) void cast_bf16_kernel(
    const float* __restrict__ in, unsigned short* __restrict__ out, int n8) {
  int i = blockIdx.x * 256 + threadIdx.x;
  if (i >= n8) return;
  size_t base = (size_t)i * 8;
  float4 a = *(const float4*)(in + base);
  float4 b = *(const float4*)(in + base + 4);
  u16x8 r;
  r[0] = f2bf(a.x); r[1] = f2bf(a.y); r[2] = f2bf(a.z); r[3] = f2bf(a.w);
  r[4] = f2bf(b.x); r[5] = f2bf(b.y); r[6] = f2bf(b.z); r[7] = f2bf(b.w);
  *(u16x8*)(out + base) = r;
}

// C = A[M,K] @ W[N,K]^T
// MODE 0: bf16 out, [B,H,S,Dh] layout   (Q, K projections)
// MODE 1: f32 out,  [M,N] row-major     (final output)
// MODE 2: bf16 out, [B,H,Dh,S] layout   (V projection, transposed)
template <int MODE>
__global__ __launch_bounds__(256) void gemm_bt(
    const unsigned short* __restrict__ A, const unsigned short* __restrict__ W,
    void* __restrict__ out, int M, int N, int K) {
  __shared__ __align__(16) unsigned short As[128 * 64];
  __shared__ __align__(16) unsigned short Bs[128 * 64];
  const int tid = threadIdx.x;
  const int lane = tid & 63;
  const int w = tid >> 6;
  const int wr = w >> 1, wc = w & 1;
  const int li = lane & 15, g = lane >> 4;
  const int bm = blockIdx.y, bn = blockIdx.x;

  f32x4 acc[4][4];
  #pragma unroll
  for (int i = 0; i < 4; i++)
    #pragma unroll
    for (int j = 0; j < 4; j++)
      #pragma unroll
      for (int r = 0; r < 4; r++) acc[i][j][r] = 0.f;

  const int srow = w * 32 + (lane >> 3);
  const int scol = (lane & 7) * 8;

  for (int k0 = 0; k0 < K; k0 += 64) {
    #pragma unroll
    for (int p = 0; p < 4; ++p) {
      int r = srow + p * 8;
      async16(&A[(size_t)(bm * 128 + r) * K + k0 + scol], &As[(w * 32 + p * 8) * 64]);
      async16(&W[(size_t)(bn * 128 + r) * K + k0 + scol], &Bs[(w * 32 + p * 8) * 64]);
    }
    __syncthreads();
    #pragma unroll
    for (int kk = 0; kk < 2; ++kk) {
      bf16x8 a[4], b[4];
      #pragma unroll
      for (int i = 0; i < 4; i++)
        a[i] = *(const bf16x8*)&As[(wr * 64 + i * 16 + li) * 64 + kk * 32 + g * 8];
      #pragma unroll
      for (int j = 0; j < 4; j++)
        b[j] = *(const bf16x8*)&Bs[(wc * 64 + j * 16 + li) * 64 + kk * 32 + g * 8];
      #pragma unroll
      for (int i = 0; i < 4; i++)
        #pragma unroll
        for (int j = 0; j < 4; j++)
          acc[i][j] = mfma16(a[i], b[j], acc[i][j]);
    }
    __syncthreads();
  }

  #pragma unroll
  for (int i = 0; i < 4; i++)
    #pragma unroll
    for (int j = 0; j < 4; j++)
      #pragma unroll
      for (int r = 0; r < 4; r++) {
        int row = bm * 128 + wr * 64 + i * 16 + g * 4 + r;
        int col = bn * 128 + wc * 64 + j * 16 + li;
        float v = acc[i][j][r];
        if constexpr (MODE == 0) {
          size_t idx = ((size_t)((row >> 11) * N_HEADS + (col >> 6)) * S_LEN +
                        (row & (S_LEN - 1))) * D_HEAD + (col & (D_HEAD - 1));
          ((unsigned short*)out)[idx] = f2bf(v);
        } else if constexpr (MODE == 1) {
          ((float*)out)[(size_t)row * N + col] = v;
        } else {
          size_t idx = ((size_t)((row >> 11) * N_HEADS + (col >> 6)) * D_HEAD +
                        (col & (D_HEAD - 1))) * S_LEN + (row & (S_LEN - 1));
          ((unsigned short*)out)[idx] = f2bf(v);
        }
      }
}

// Flash attention, swapped-operand 32x32 structure (m214 style).
// grid (S/128, B*H), 256 thr = 4 waves; wave owns 32 q-rows.
// qh,kh: [B,H,S,64] bf16. vt: [B,H,64,S] bf16. xout: [B,S,E] bf16.
// S^T = mfma32(K, Q): lane holds S[key=crow(r,hi)][q=lane&31].
// O^T = mfma32(V^T, P): lane holds O[d=crow(r,hi)+32*dt][q=lane&31].
__global__ __launch_bounds__(256) void attn_kernel(
    const unsigned short* __restrict__ qh, const unsigned short* __restrict__ kh,
    const unsigned short* __restrict__ vt, unsigned short* __restrict__ xout) {
  __shared__ float O_lds[4][32 * 65];
  const int lane = threadIdx.x & 63;
  const int w = threadIdx.x >> 6;
  const int l32 = lane & 31;
  const int hi = lane >> 5;
  const int bh = blockIdx.y;
  const int qb = blockIdx.x * 128 + w * 32;

  const unsigned short* Q = qh + (size_t)bh * S_LEN * D_HEAD;
  const unsigned short* Kp = kh + (size_t)bh * S_LEN * D_HEAD;
  const unsigned short* Vt = vt + (size_t)bh * D_HEAD * S_LEN;

  // Q B-frags: lane holds Q[qb+l32][d = ks*16 + hi*8 + j]
  bf16x8 qf[4];
  #pragma unroll
  for (int ks = 0; ks < 4; ks++)
    qf[ks] = *(const bf16x8*)&Q[(qb + l32) * 64 + ks * 16 + hi * 8];

  f32x16 o0, o1;
  #pragma unroll
  for (int r = 0; r < 16; r++) { o0[r] = 0.f; o1[r] = 0.f; }
  float m2 = -1e30f;   // running max in log2 domain
  float lsum = 0.f;

  for (int kv = 0; kv < S_LEN; kv += 32) {
    // K A-frags: lane holds K[kv+l32][d = ks*16 + hi*8 + j]
    bf16x8 kf[4];
    #pragma unroll
    for (int ks = 0; ks < 4; ks++)
      kf[ks] = *(const bf16x8*)&Kp[(kv + l32) * 64 + ks * 16 + hi * 8];

    f32x16 s;
    #pragma unroll
    for (int r = 0; r < 16; r++) s[r] = 0.f;
    #pragma unroll
    for (int ks = 0; ks < 4; ks++) s = mfma32(kf[ks], qf[ks], s);
    // s[r] = S^T[key = kv + (r&3)+8*(r>>2)+4*hi][q = qb+l32]

    const float cs = 0.18033688011112042f;  // (1/sqrt(64)) * log2(e)
    float p[16];
    #pragma unroll
    for (int r = 0; r < 16; r++) p[r] = s[r] * cs;
    float mx = fmaxf(p[0], p[1]);
    #pragma unroll
    for (int r = 2; r < 16; r++) mx = fmaxf(mx, p[r]);
    mx = fmaxf(mx, __shfl_xor(mx, 32));
    float mn = fmaxf(m2, mx);
    float sc = __builtin_amdgcn_exp2f(m2 - mn);
    float ts = 0.f;
    #pragma unroll
    for (int r = 0; r < 16; r++) {
      p[r] = __builtin_amdgcn_exp2f(p[r] - mn);
      ts += p[r];
    }
    ts += __shfl_xor(ts, 32);
    lsum = lsum * sc + ts;
    m2 = mn;
    #pragma unroll
    for (int r = 0; r < 16; r++) { o0[r] *= sc; o1[r] *= sc; }

    // P -> bf16 A-frag layout via cvt_pk + permlane32_swap (T12).
    // own keys per pair t: c[t] = (key 4hi+.., ..) per crow mapping.
    unsigned c[8];
    #pragma unroll
    for (int t = 0; t < 8; t++)
      asm("v_cvt_pk_bf16_f32 %0, %1, %2"
          : "=v"(c[t]) : "v"(p[2 * t]), "v"(p[2 * t + 1]));
    // after swap: c0..c3 = PA0 words (keys hi*8+0..7), c4..c7 = PA1 (keys 16+hi*8+0..7)
    asm("v_permlane32_swap_b32 %0, %1" : "+v"(c[0]), "+v"(c[2]));
    asm("v_permlane32_swap_b32 %0, %1" : "+v"(c[1]), "+v"(c[3]));
    asm("v_permlane32_swap_b32 %0, %1" : "+v"(c[4]), "+v"(c[6]));
    asm("v_permlane32_swap_b32 %0, %1" : "+v"(c[5]), "+v"(c[7]));
    u32x4 t0 = {c[0], c[1], c[2], c[3]};
    u32x4 t1 = {c[4], c[5], c[6], c[7]};
    bf16x8 pa0 = __builtin_bit_cast(bf16x8, t0);
    bf16x8 pa1 = __builtin_bit_cast(bf16x8, t1);

    // V^T A-frags: lane holds V[k = kv + ks2*16 + hi*8 + j][d = dt*32 + l32]
    bf16x8 v00 = *(const bf16x8*)&Vt[(size_t)l32 * S_LEN + kv + hi * 8];
    bf16x8 v01 = *(const bf16x8*)&Vt[(size_t)l32 * S_LEN + kv + 16 + hi * 8];
    bf16x8 v10 = *(const bf16x8*)&Vt[(size_t)(32 + l32) * S_LEN + kv + hi * 8];
    bf16x8 v11 = *(const bf16x8*)&Vt[(size_t)(32 + l32) * S_LEN + kv + 16 + hi * 8];
    o0 = mfma32(v00, pa0, o0);
    o0 = mfma32(v01, pa1, o0);
    o1 = mfma32(v10, pa0, o1);
    o1 = mfma32(v11, pa1, o1);
  }

  // Epilogue: normalize, transpose O^T -> O via padded LDS, coalesced store.
  float inv = 1.0f / lsum;
  #pragma unroll
  for (int r = 0; r < 16; r++) {
    int d = (r & 3) + 8 * (r >> 2) + 4 * hi;
    O_lds[w][l32 * 65 + d] = o0[r] * inv;
    O_lds[w][l32 * 65 + 32 + d] = o1[r] * inv;
  }
  const int qr = lane >> 1;
  const int coff = (lane & 1) * 32;
  const int b = bh >> 4, h = bh & 15;
  unsigned short* dst =
      &xout[((size_t)(b * S_LEN) + qb + qr) * D_EMBD + h * 64 + coff];
  #pragma unroll
  for (int t = 0; t < 4; t++) {
    u16x8 rr;
    #pragma unroll
    for (int j = 0; j < 8; j++)
      rr[j] = f2bf(O_lds[w][qr * 65 + coff + t * 8 + j]);
    *(u16x8*)(dst + t * 8) = rr;
  }
}

extern "C" void kernel_launch(void* const* d_in, const int* in_sizes, int n_in,
                              void* d_out, int out_size, void* d_ws, size_t ws_size,
                              hipStream_t stream) {
  const float* q   = (const float*)d_in[0];
  const float* k   = (const float*)d_in[1];
  const float* v   = (const float*)d_in[2];
  const float* wqf = (const float*)d_in[3];
  const float* wkf = (const float*)d_in[4];
  const float* wvf = (const float*)d_in[5];
  const float* wof = (const float*)d_in[6];

  char* ws = (char*)d_ws;
  unsigned short* castbuf = (unsigned short*)(ws);                 // 16 MB
  unsigned short* qh = (unsigned short*)(ws + (16u << 20));        // 16 MB
  unsigned short* kh = (unsigned short*)(ws + (32u << 20));        // 16 MB
  unsigned short* vt = (unsigned short*)(ws + (48u << 20));        // 16 MB
  unsigned short* ax = (unsigned short*)(ws + (64u << 20));        // 16 MB
  unsigned short* wq = (unsigned short*)(ws + (80u << 20));        // 2 MB
  unsigned short* wk = wq + (1u << 20);
  unsigned short* wv = wk + (1u << 20);
  unsigned short* wo = wv + (1u << 20);

  const int MK8 = M_TOT * D_EMBD / 8;   // 1048576
  const int WK8 = D_EMBD * D_EMBD / 8;  // 131072

  cast_bf16_kernel<<<WK8 / 256, 256, 0, stream>>>(wqf, wq, WK8);
  cast_bf16_kernel<<<WK8 / 256, 256, 0, stream>>>(wkf, wk, WK8);
  cast_bf16_kernel<<<WK8 / 256, 256, 0, stream>>>(wvf, wv, WK8);
  cast_bf16_kernel<<<WK8 / 256, 256, 0, stream>>>(wof, wo, WK8);

  dim3 gg(D_EMBD / 128, M_TOT / 128);  // (8, 64)

  cast_bf16_kernel<<<MK8 / 256, 256, 0, stream>>>(q, castbuf, MK8);
  gemm_bt<0><<<gg, 256, 0, stream>>>(castbuf, wq, qh, M_TOT, D_EMBD, D_EMBD);
  cast_bf16_kernel<<<MK8 / 256, 256, 0, stream>>>(k, castbuf, MK8);
  gemm_bt<0><<<gg, 256, 0, stream>>>(castbuf, wk, kh, M_TOT, D_EMBD, D_EMBD);
  cast_bf16_kernel<<<MK8 / 256, 256, 0, stream>>>(v, castbuf, MK8);
  gemm_bt<2><<<gg, 256, 0, stream>>>(castbuf, wv, vt, M_TOT, D_EMBD, D_EMBD);

  attn_kernel<<<dim3(S_LEN / 128, B_SZ * N_HEADS), 256, 0, stream>>>(qh, kh, vt, ax);

  gemm_bt<1><<<gg, 256, 0, stream>>>(ax, wo, d_out, M_TOT, D_EMBD, D_EMBD);
}